// Round 12
// baseline (390.365 us; speedup 1.0000x reference)
//
#include <hip/hip_runtime.h>

#define NN 50000
#define DIN 128
#define DH  128
#define DOUT 40
#define BN_EPS 1e-5f

__device__ __forceinline__ void atomAddF(float* p, float v) {
  unsafeAtomicAdd(p, v);   // native global_atomic_add_f32 on gfx950
}

// bf16 storage helpers (RNE), fp32 accumulation everywhere.
__device__ __forceinline__ unsigned short f2bf(float f) {
  unsigned int u = __float_as_uint(f);
  return (unsigned short)((u + 0x7FFFu + ((u >> 16) & 1u)) >> 16);
}
__device__ __forceinline__ float bflo(unsigned int u) {   // low ushort -> float
  return __uint_as_float(u << 16);
}
__device__ __forceinline__ float bfhi(unsigned int u) {   // high ushort -> float
  return __uint_as_float(u & 0xFFFF0000u);
}

// 1. int in-degree histogram over dst (self-loop folded in later)
__global__ void k_deg(const int* __restrict__ dst, int* __restrict__ deg, int E) {
  int e = blockIdx.x * blockDim.x + threadIdx.x;
  if (e < E) atomicAdd(&deg[dst[e]], 1);
}

// 2. CSR offsets via wave-aggregated atomic counter (order-free, scan-free).
__global__ void k_off(const int* __restrict__ deg, int* __restrict__ off,
                      int* __restrict__ cur, float* __restrict__ dinv,
                      int* __restrict__ counter) {
  int i = blockIdx.x * 256 + threadIdx.x;
  int lane = threadIdx.x & 63;
  int d = (i < NN) ? deg[i] : 0;
  int pre = d;
#pragma unroll
  for (int o = 1; o < 64; o <<= 1) {
    int v = __shfl_up(pre, o);
    if (lane >= o) pre += v;
  }
  int tot = __shfl(pre, 63);            // wave total
  int base = 0;
  if (lane == 63) base = atomicAdd(counter, tot);
  base = __shfl(base, 63);
  int o0 = base + pre - d;              // exclusive within wave
  if (i < NN) {
    off[i] = o0; cur[i] = o0;
    dinv[i] = rsqrtf((float)d + 1.0f);
  }
}

// 3. CSR fill: group src indices by dst
__global__ void k_fill(const int* __restrict__ src, const int* __restrict__ dst,
                       int* __restrict__ cur, int* __restrict__ csr, int E) {
  int e = blockIdx.x * blockDim.x + threadIdx.x;
  if (e >= E) return;
  int pos = atomicAdd(&cur[dst[e]], 1);
  csr[pos] = src[e];
}

// 4. Y1[i][j] = bf16( dinv[i] * sum_k X[i][k] * W1[k][j] )
__global__ __launch_bounds__(256) void k_gemm1(const float* __restrict__ X,
                                               const float* __restrict__ W,
                                               const float* __restrict__ dinv,
                                               unsigned short* __restrict__ Y) {
  int t = threadIdx.x;
  int tx = t & 31;          // col quad 0..31 -> c0 = tx*4
  int ty = t >> 5;          // 0..7 -> 8 rows each
  int r0 = blockIdx.x * 64 + ty * 8;
  int c0 = tx * 4;
  const float4* W4 = (const float4*)W;   // quad index = k*32 + tx

  const float* xp[8];
#pragma unroll
  for (int r = 0; r < 8; ++r) {
    int row = r0 + r;
    if (row >= NN) row = NN - 1;         // clamp: safe load, store guarded
    xp[r] = X + (size_t)row * DIN;
  }

  float acc[8][4] = {};
  for (int k = 0; k < DIN; k += 4) {
    float4 w0 = W4[(k + 0) * 32 + tx];
    float4 w1 = W4[(k + 1) * 32 + tx];
    float4 w2 = W4[(k + 2) * 32 + tx];
    float4 w3 = W4[(k + 3) * 32 + tx];
#pragma unroll
    for (int r = 0; r < 8; ++r) {
      float4 xv = *(const float4*)(xp[r] + k);
      acc[r][0] = fmaf(xv.x, w0.x, fmaf(xv.y, w1.x, fmaf(xv.z, w2.x, fmaf(xv.w, w3.x, acc[r][0]))));
      acc[r][1] = fmaf(xv.x, w0.y, fmaf(xv.y, w1.y, fmaf(xv.z, w2.y, fmaf(xv.w, w3.y, acc[r][1]))));
      acc[r][2] = fmaf(xv.x, w0.z, fmaf(xv.y, w1.z, fmaf(xv.z, w2.z, fmaf(xv.w, w3.z, acc[r][2]))));
      acc[r][3] = fmaf(xv.x, w0.w, fmaf(xv.y, w1.w, fmaf(xv.z, w2.w, fmaf(xv.w, w3.w, acc[r][3]))));
    }
  }
#pragma unroll
  for (int r = 0; r < 8; ++r) {
    int row = r0 + r;
    if (row < NN) {
      float dv = dinv[row];
      ushort4 st;
      st.x = f2bf(acc[r][0] * dv); st.y = f2bf(acc[r][1] * dv);
      st.z = f2bf(acc[r][2] * dv); st.w = f2bf(acc[r][3] * dv);
      *(ushort4*)(Y + (size_t)row * DH + c0) = st;
    }
  }
}

// 5. pull-mode aggregation layer1 + finalize + fused BN column stats.
//    4 nodes per wave, quarter-wave (16 lanes) per node; one dwordx4 gather
//    fetches 4 rows (one per quarter) -> ~3x fewer gather instructions.
//    csr indices come via a 64-wide VECTOR preload + shfl(bpermute) with a
//    computed source lane (no scalar-load round trips). Each quarter walks
//    its own segment in ascending k: every output column's add chain is
//    bit-identical to round 10 (self first, then neighbors in csr order).
__global__ __launch_bounds__(256) void k_pull1(
    const int* __restrict__ off, const int* __restrict__ deg,
    const int* __restrict__ csr, const uint4* __restrict__ Yq,   // row n = Yq[n*16..]
    const float* __restrict__ dinv, const float* __restrict__ b1,
    float* __restrict__ Z, float* __restrict__ colsum,
    float* __restrict__ colsumsq) {
  __shared__ float s_sum[4][128], s_sq[4][128];
  int t = threadIdx.x, l = t & 63, wid = t >> 6;
  int sub = l & 15;                     // 16B-slice index within a row
  int n = blockIdx.x * 16 + wid * 4 + (l >> 4);   // NN = 3125*16, exact

  // self loop FIRST (order matters)
  uint4 ys = Yq[(size_t)n * 16 + sub];
  float a0 = bflo(ys.x), a1 = bfhi(ys.x), a2 = bflo(ys.y), a3 = bfhi(ys.y);
  float a4 = bflo(ys.z), a5 = bfhi(ys.z), a6 = bflo(ys.w), a7 = bfhi(ys.w);

  int o = off[n], dg = deg[n];
  int mr = max(dg, __shfl_xor(dg, 16));
  mr = max(mr, __shfl_xor(mr, 32));     // wave-max degree (uniform)

  for (int kb = 0; kb < mr; kb += 16) {
    int pos = kb + sub;
    int myidx = csr[o + ((pos < dg) ? pos : 0)];  // 16 indices per quarter
    int rem = dg - kb;                            // quarter-uniform
    int kmax = mr - kb; if (kmax > 16) kmax = 16;
    for (int kk = 0; kk < kmax; ++kk) {
      int sN = __shfl(myidx, (l & 48) + kk);      // bpermute within quarter
      if (kk < rem) {
        uint4 y = Yq[(size_t)sN * 16 + sub];
        a0 += bflo(y.x); a1 += bfhi(y.x);         // strict ascending k
        a2 += bflo(y.y); a3 += bfhi(y.y);
        a4 += bflo(y.z); a5 += bfhi(y.z);
        a6 += bflo(y.w); a7 += bfhi(y.w);
      }
    }
  }

  float dn = dinv[n];
  const float4* b4 = (const float4*)b1;
  float4 bA = b4[sub * 2], bB = b4[sub * 2 + 1];
  float z0 = fmaf(dn, a0, bA.x), z1 = fmaf(dn, a1, bA.y);
  float z2 = fmaf(dn, a2, bA.z), z3 = fmaf(dn, a3, bA.w);
  float z4 = fmaf(dn, a4, bB.x), z5 = fmaf(dn, a5, bB.y);
  float z6 = fmaf(dn, a6, bB.z), z7 = fmaf(dn, a7, bB.w);
  float4* Z4 = (float4*)Z;
  Z4[(size_t)n * 32 + sub * 2 + 0] = make_float4(z0, z1, z2, z3);
  Z4[(size_t)n * 32 + sub * 2 + 1] = make_float4(z4, z5, z6, z7);

  // BN stats: fold the 4 nodes of this wave via xor-shfl, then LDS + atomics.
  float s[8] = {z0, z1, z2, z3, z4, z5, z6, z7};
  float q[8];
#pragma unroll
  for (int j = 0; j < 8; ++j) q[j] = s[j] * s[j];
#pragma unroll
  for (int j = 0; j < 8; ++j) {
    s[j] += __shfl_xor(s[j], 16); s[j] += __shfl_xor(s[j], 32);
    q[j] += __shfl_xor(q[j], 16); q[j] += __shfl_xor(q[j], 32);
  }
  if (l < 16) {
#pragma unroll
    for (int j = 0; j < 8; ++j) {
      s_sum[wid][sub * 8 + j] = s[j];
      s_sq[wid][sub * 8 + j]  = q[j];
    }
  }
  __syncthreads();
  if (t < 128) {
    atomAddF(&colsum[t],   s_sum[0][t] + s_sum[1][t] + s_sum[2][t] + s_sum[3][t]);
    atomAddF(&colsumsq[t], s_sq[0][t] + s_sq[1][t] + s_sq[2][t] + s_sq[3][t]);
  }
}

// 6. BN scale/shift from raw moments (biased var, as torch BN)
__global__ void k_bn(const float* __restrict__ colsum, const float* __restrict__ colsumsq,
                     const float* __restrict__ gamma, const float* __restrict__ beta,
                     float* __restrict__ scale, float* __restrict__ shift) {
  int j = threadIdx.x;
  float mean = colsum[j] * (1.0f / NN);
  float var  = colsumsq[j] * (1.0f / NN) - mean * mean;
  float sc = gamma[j] * rsqrtf(var + BN_EPS);
  scale[j] = sc;
  shift[j] = beta[j] - mean * sc;
}

// 7. Y2[i][j] = bf16( dinv[i] * sum_k relu(Z[i][k]*scale[k]+shift[k]) * W2[k][j] )
__global__ __launch_bounds__(256) void k_gemm2(const float* __restrict__ Z,
                                               const float* __restrict__ W2,
                                               const float* __restrict__ scale,
                                               const float* __restrict__ shift,
                                               const float* __restrict__ dinv,
                                               unsigned short* __restrict__ Y2) {
  int t = threadIdx.x;
  if (t >= 250) return;
  int tx = t % 10;          // col quad 0..9 -> c0 = tx*4 (DOUT=40)
  int ty = t / 10;          // 0..24 -> 4 rows each -> 100 rows/block
  int r0 = blockIdx.x * 100 + ty * 4;   // grid=500 -> exactly 50000 rows
  int c0 = tx * 4;
  const float4* W4  = (const float4*)W2;     // quad index = k*10 + tx
  const float4* sc4 = (const float4*)scale;
  const float4* sh4 = (const float4*)shift;

  const float* zp[4];
#pragma unroll
  for (int r = 0; r < 4; ++r) zp[r] = Z + (size_t)(r0 + r) * DH;

  float acc[4][4] = {};
  for (int k4 = 0; k4 < DH / 4; ++k4) {
    int k = k4 * 4;
    float4 sc = sc4[k4], sh = sh4[k4];
    float4 w0 = W4[(k + 0) * 10 + tx];
    float4 w1 = W4[(k + 1) * 10 + tx];
    float4 w2 = W4[(k + 2) * 10 + tx];
    float4 w3 = W4[(k + 3) * 10 + tx];
#pragma unroll
    for (int r = 0; r < 4; ++r) {
      float4 zv = *(const float4*)(zp[r] + k);
      float x0 = fmaxf(fmaf(zv.x, sc.x, sh.x), 0.f);
      float x1 = fmaxf(fmaf(zv.y, sc.y, sh.y), 0.f);
      float x2 = fmaxf(fmaf(zv.z, sc.z, sh.z), 0.f);
      float x3 = fmaxf(fmaf(zv.w, sc.w, sh.w), 0.f);
      acc[r][0] = fmaf(x0, w0.x, fmaf(x1, w1.x, fmaf(x2, w2.x, fmaf(x3, w3.x, acc[r][0]))));
      acc[r][1] = fmaf(x0, w0.y, fmaf(x1, w1.y, fmaf(x2, w2.y, fmaf(x3, w3.y, acc[r][1]))));
      acc[r][2] = fmaf(x0, w0.z, fmaf(x1, w1.z, fmaf(x2, w2.z, fmaf(x3, w3.z, acc[r][2]))));
      acc[r][3] = fmaf(x0, w0.w, fmaf(x1, w1.w, fmaf(x2, w2.w, fmaf(x3, w3.w, acc[r][3]))));
    }
  }
#pragma unroll
  for (int r = 0; r < 4; ++r) {
    int row = r0 + r;
    float dv = dinv[row];
    ushort4 st;
    st.x = f2bf(acc[r][0] * dv); st.y = f2bf(acc[r][1] * dv);
    st.z = f2bf(acc[r][2] * dv); st.w = f2bf(acc[r][3] * dv);
    *(ushort4*)(Y2 + (size_t)row * DOUT + c0) = st;
  }
}

// 8. pull-mode aggregation layer2: 2 nodes per wave, 20-lane slice per node
//    (uint = 2 bf16 cols per lane), vector csr preload + bpermute broadcast;
//    per-node ascending-k order (bit-identical chains); writes fp32 d_out.
__global__ __launch_bounds__(256) void k_pull2(
    const int* __restrict__ off, const int* __restrict__ deg,
    const int* __restrict__ csr, const unsigned int* __restrict__ Yu2, // row n = Yu2[n*20..]
    const float* __restrict__ dinv, const float* __restrict__ b2,
    float* __restrict__ out) {
  int t = threadIdx.x, l = t & 63, wid = t >> 6;
  int il = l & 31;
  int n = blockIdx.x * 8 + wid * 2 + (l >> 5);   // NN = 6250*8, exact
  bool act = il < 20;
  int c0 = il * 2;

  float a0 = 0.f, a1 = 0.f;
  if (act) {                             // self loop FIRST
    unsigned int us = Yu2[(size_t)n * 20 + il];
    a0 = bflo(us); a1 = bfhi(us);
  }
  int o = off[n], dg = deg[n];
  int mr = max(dg, __shfl_xor(dg, 32));  // wave-max degree (uniform)

  for (int kb = 0; kb < mr; kb += 32) {
    int pos = kb + il;
    int myidx = csr[o + ((pos < dg) ? pos : 0)];  // 32 indices per half
    int rem = dg - kb;                            // half-uniform
    int kmax = mr - kb; if (kmax > 32) kmax = 32;
    for (int kk = 0; kk < kmax; ++kk) {
      int sN = __shfl(myidx, (l & 32) + kk);      // bpermute within half
      if (act && kk < rem) {
        unsigned int y = Yu2[(size_t)sN * 20 + il];
        a0 += bflo(y); a1 += bfhi(y);             // strict ascending k
      }
    }
  }
  if (act) {
    float dn = dinv[n];
    float2 r = make_float2(fmaf(dn, a0, b2[c0]), fmaf(dn, a1, b2[c0 + 1]));
    ((float2*)(out + (size_t)n * DOUT))[il] = r;
  }
}

extern "C" void kernel_launch(void* const* d_in, const int* in_sizes, int n_in,
                              void* d_out, int out_size, void* d_ws, size_t ws_size,
                              hipStream_t stream) {
  const float* X     = (const float*)d_in[0];
  const float* W1    = (const float*)d_in[1];
  const float* b1    = (const float*)d_in[2];
  const float* gamma = (const float*)d_in[3];
  const float* beta  = (const float*)d_in[4];
  const float* W2    = (const float*)d_in[5];
  const float* b2    = (const float*)d_in[6];
  const int*   edges = (const int*)d_in[7];
  int E = in_sizes[7] / 2;
  const int* src = edges;
  const int* dst = edges + E;

  int E4 = ((E + 64) + 3) & ~3;                  // +64 pad for masked preloads
  int* i_deg = (int*)d_ws;                       // NN ints, stride 50048
  int* i_off = i_deg + 50048;
  int* i_cur = i_off + 50048;
  int* i_cnt = i_cur + 50016;                    // counter in i_cur's padding
  int* i_csr = i_cur + 50048;                    // E ints (+pad)
  float* f_dinv = (float*)(i_csr + E4);          // NN floats
  unsigned short* u_Y1 = (unsigned short*)(f_dinv + 50048);   // NN*DH bf16
  float* f_Z  = (float*)(u_Y1 + (size_t)NN * DH);             // NN*DH fp32
  float* f_st = f_Z + (size_t)NN * DH;           // colsum|colsumsq|scale|shift
  unsigned short* u_Y2 = u_Y1;                   // alias: Y1 dead after k_pull1

  hipMemsetAsync(i_deg, 0, 50000 * sizeof(int), stream);
  hipMemsetAsync(i_cnt, 0, sizeof(int), stream);
  hipMemsetAsync(f_st, 0, 256 * sizeof(float), stream);

  k_deg <<<(E + 255) / 256, 256, 0, stream>>>(dst, i_deg, E);
  k_off <<<(NN + 255) / 256, 256, 0, stream>>>(i_deg, i_off, i_cur, f_dinv, i_cnt);
  k_fill<<<(E + 255) / 256, 256, 0, stream>>>(src, dst, i_cur, i_csr, E);
  k_gemm1<<<(NN + 63) / 64, 256, 0, stream>>>(X, W1, f_dinv, u_Y1);
  k_pull1<<<NN / 16, 256, 0, stream>>>(i_off, i_deg, i_csr,
                                       (const uint4*)u_Y1, f_dinv, b1,
                                       f_Z, f_st, f_st + 128);
  k_bn<<<1, 128, 0, stream>>>(f_st, f_st + 128, gamma, beta, f_st + 256, f_st + 384);
  k_gemm2<<<500, 256, 0, stream>>>(f_Z, W2, f_st + 256, f_st + 384, f_dinv, u_Y2);
  k_pull2<<<NN / 8, 256, 0, stream>>>(i_off, i_deg, i_csr,
                                      (const unsigned int*)u_Y2, f_dinv, b2,
                                      (float*)d_out);
}